// Round 1
// baseline (2579.241 us; speedup 1.0000x reference)
//
#include <hip/hip_runtime.h>

#define B_ 16
#define T_ 1024
#define S_ 1024
#define D_ 768      // ENC == DEC
#define K3_ 1536    // D_ + D_
#define BS_ (B_ * S_)   // 16384
#define BD_ (B_ * D_)   // 12288

// ---------------------------------------------------------------------------
// GEMM1: scores[t,s] = sum_k inputs[b,t,k] * ctx[b,s,k]   (NT)
// writes directly into out2 laid out [T, B, S]
// ---------------------------------------------------------------------------
__global__ __launch_bounds__(256) void gemm_scores(
    const float* __restrict__ inp, const float* __restrict__ ctx,
    float* __restrict__ out2)
{
    const int b  = blockIdx.z;
    const int t0 = blockIdx.y * 64;
    const int s0 = blockIdx.x * 64;
    const float* A  = inp + (size_t)b * T_ * D_;
    const float* Bm = ctx + (size_t)b * S_ * D_;

    __shared__ float As[64 * 20];
    __shared__ float Bs[64 * 20];

    const int tid = threadIdx.x;
    const int lr = tid >> 2;          // 0..63
    const int lc = (tid & 3) * 4;     // 0,4,8,12
    const int r0 = (tid >> 4) * 4;    // 0..60
    const int c0 = (tid & 15) * 4;    // 0..60

    float acc[4][4] = {};

    for (int kb = 0; kb < D_; kb += 16) {
        float4 a4 = *(const float4*)(A  + (size_t)(t0 + lr) * D_ + kb + lc);
        float4 b4 = *(const float4*)(Bm + (size_t)(s0 + lr) * D_ + kb + lc);
        __syncthreads();
        *(float4*)&As[lr * 20 + lc] = a4;
        *(float4*)&Bs[lr * 20 + lc] = b4;
        __syncthreads();
#pragma unroll
        for (int kk = 0; kk < 16; kk += 4) {
            float4 av[4], bv[4];
#pragma unroll
            for (int i = 0; i < 4; i++) av[i] = *(float4*)&As[(r0 + i) * 20 + kk];
#pragma unroll
            for (int j = 0; j < 4; j++) bv[j] = *(float4*)&Bs[(c0 + j) * 20 + kk];
#pragma unroll
            for (int i = 0; i < 4; i++)
#pragma unroll
                for (int j = 0; j < 4; j++) {
                    acc[i][j] += av[i].x * bv[j].x;
                    acc[i][j] += av[i].y * bv[j].y;
                    acc[i][j] += av[i].z * bv[j].z;
                    acc[i][j] += av[i].w * bv[j].w;
                }
        }
    }
#pragma unroll
    for (int i = 0; i < 4; i++) {
        float4 o = make_float4(acc[i][0], acc[i][1], acc[i][2], acc[i][3]);
        *(float4*)(out2 + (size_t)(t0 + r0 + i) * BS_ + (size_t)b * S_ + s0 + c0) = o;
    }
}

// ---------------------------------------------------------------------------
// Softmax over S, in place on out2 rows (row = out2[t*B*S + b*S + :])
// ---------------------------------------------------------------------------
__global__ __launch_bounds__(256) void softmax_rows(float* __restrict__ av)
{
    const int bid = blockIdx.x;
    const int b = bid & (B_ - 1);
    const int t = bid / B_;
    float* row = av + (size_t)t * BS_ + (size_t)b * S_;
    const int tid = threadIdx.x;

    float4 v = ((float4*)row)[tid];
    float m = fmaxf(fmaxf(v.x, v.y), fmaxf(v.z, v.w));

    __shared__ float red[256];
    red[tid] = m;
    __syncthreads();
    for (int off = 128; off > 0; off >>= 1) {
        if (tid < off) red[tid] = fmaxf(red[tid], red[tid + off]);
        __syncthreads();
    }
    m = red[0];
    __syncthreads();

    float4 e;
    e.x = __expf(v.x - m); e.y = __expf(v.y - m);
    e.z = __expf(v.z - m); e.w = __expf(v.w - m);
    float s = e.x + e.y + e.z + e.w;
    red[tid] = s;
    __syncthreads();
    for (int off = 128; off > 0; off >>= 1) {
        if (tid < off) red[tid] += red[tid + off];
        __syncthreads();
    }
    const float inv = 1.0f / red[0];
    e.x *= inv; e.y *= inv; e.z *= inv; e.w *= inv;
    ((float4*)row)[tid] = e;
}

// ---------------------------------------------------------------------------
// gate[b,s] = sigmoid(sum_t av[t,b,s]) * (1/S)      (pooled == 1/S exactly)
// ---------------------------------------------------------------------------
__global__ __launch_bounds__(256) void colsum_gate(
    const float* __restrict__ av, float* __restrict__ gate)
{
    const int b = blockIdx.y;
    const int s = blockIdx.x * 256 + threadIdx.x;
    const float* col = av + (size_t)b * S_ + s;
    float sum = 0.0f;
#pragma unroll 8
    for (int t = 0; t < T_; t++) sum += col[(size_t)t * BS_];
    const float g = 1.0f / (1.0f + __expf(-sum));
    gate[b * S_ + s] = g * (1.0f / (float)S_);
}

// ---------------------------------------------------------------------------
// av_g = av * gate[b,s]  (in place on out2)
// ---------------------------------------------------------------------------
__global__ __launch_bounds__(256) void scale_av(
    float* __restrict__ av, const float* __restrict__ gate)
{
    const size_t i4 = (size_t)blockIdx.x * 256 + threadIdx.x;   // float4 index
    const size_t flat = i4 * 4;
    const int s = (int)(flat & (S_ - 1));
    const int b = (int)((flat >> 10) & (B_ - 1));
    float4 v = ((float4*)av)[i4];
    const float4 g = ((const float4*)gate)[(b * S_ + s) >> 2];
    v.x *= g.x; v.y *= g.y; v.z *= g.z; v.w *= g.w;
    ((float4*)av)[i4] = v;
}

// ---------------------------------------------------------------------------
// GEMM2: c[b,t,d] = (sum_s av_g[t,b,s] * ctx[b,s,d]) * w_scale + b_scale
// A is NT-ish (s contiguous), B is NN (stage transposed into LDS)
// ---------------------------------------------------------------------------
__global__ __launch_bounds__(256) void gemm_ctx(
    const float* __restrict__ avg, const float* __restrict__ ctx,
    const float* __restrict__ w_scale, const float* __restrict__ b_scale,
    float* __restrict__ c_ws)
{
    const int b  = blockIdx.z;
    const int t0 = blockIdx.y * 64;
    const int d0 = blockIdx.x * 64;

    __shared__ float As[64 * 20];
    __shared__ float Bs[64 * 20];   // [d][s] transposed

    const int tid = threadIdx.x;
    const int lr = tid >> 2;          // 0..63 (A rows)
    const int lc = (tid & 3) * 4;     // 0,4,8,12 (A cols / s)
    const int br = tid >> 4;          // 0..15 (B rows / s)
    const int bc = (tid & 15) * 4;    // 0..60 (B cols / d)
    const int r0 = (tid >> 4) * 4;
    const int c0 = (tid & 15) * 4;

    float acc[4][4] = {};

    for (int sb = 0; sb < S_; sb += 16) {
        float4 a4 = *(const float4*)(avg + (size_t)(t0 + lr) * BS_ + (size_t)b * S_ + sb + lc);
        float4 b4 = *(const float4*)(ctx + (size_t)b * S_ * D_ + (size_t)(sb + br) * D_ + d0 + bc);
        __syncthreads();
        *(float4*)&As[lr * 20 + lc] = a4;
        Bs[(bc + 0) * 20 + br] = b4.x;
        Bs[(bc + 1) * 20 + br] = b4.y;
        Bs[(bc + 2) * 20 + br] = b4.z;
        Bs[(bc + 3) * 20 + br] = b4.w;
        __syncthreads();
#pragma unroll
        for (int kk = 0; kk < 16; kk += 4) {
            float4 av4[4], bv[4];
#pragma unroll
            for (int i = 0; i < 4; i++) av4[i] = *(float4*)&As[(r0 + i) * 20 + kk];
#pragma unroll
            for (int j = 0; j < 4; j++) bv[j] = *(float4*)&Bs[(c0 + j) * 20 + kk];
#pragma unroll
            for (int i = 0; i < 4; i++)
#pragma unroll
                for (int j = 0; j < 4; j++) {
                    acc[i][j] += av4[i].x * bv[j].x;
                    acc[i][j] += av4[i].y * bv[j].y;
                    acc[i][j] += av4[i].z * bv[j].z;
                    acc[i][j] += av4[i].w * bv[j].w;
                }
        }
    }
    const float ws = w_scale[0], bs = b_scale[0];
#pragma unroll
    for (int i = 0; i < 4; i++) {
        float4 o = make_float4(acc[i][0] * ws + bs, acc[i][1] * ws + bs,
                               acc[i][2] * ws + bs, acc[i][3] * ws + bs);
        *(float4*)(c_ws + ((size_t)b * T_ + t0 + r0 + i) * D_ + d0 + c0) = o;
    }
}

// ---------------------------------------------------------------------------
// GEMM3: h[n,d] = prelu( sum_k concat[n,k] * W[d,k] + b_out[d] )
// concat[n,k] = k < D ? c_ws[n,k] : inputs[n,k-D];  n = b*T + t
// write to out0 laid out [T, B, D]
// ---------------------------------------------------------------------------
__global__ __launch_bounds__(256) void gemm_out(
    const float* __restrict__ c_ws, const float* __restrict__ inp,
    const float* __restrict__ W, const float* __restrict__ bias,
    const float* __restrict__ prelu_a, float* __restrict__ out0)
{
    const int n0 = blockIdx.y * 64;
    const int d0 = blockIdx.x * 64;

    __shared__ float As[64 * 20];
    __shared__ float Bs[64 * 20];

    const int tid = threadIdx.x;
    const int lr = tid >> 2;
    const int lc = (tid & 3) * 4;
    const int r0 = (tid >> 4) * 4;
    const int c0 = (tid & 15) * 4;

    float acc[4][4] = {};

    for (int kb = 0; kb < K3_; kb += 16) {
        const int k = kb + lc;
        const float* arow = (k < D_) ? (c_ws + (size_t)(n0 + lr) * D_ + k)
                                     : (inp + (size_t)(n0 + lr) * D_ + (k - D_));
        float4 a4 = *(const float4*)arow;
        float4 b4 = *(const float4*)(W + (size_t)(d0 + lr) * K3_ + kb + lc);
        __syncthreads();
        *(float4*)&As[lr * 20 + lc] = a4;
        *(float4*)&Bs[lr * 20 + lc] = b4;
        __syncthreads();
#pragma unroll
        for (int kk = 0; kk < 16; kk += 4) {
            float4 av[4], bv[4];
#pragma unroll
            for (int i = 0; i < 4; i++) av[i] = *(float4*)&As[(r0 + i) * 20 + kk];
#pragma unroll
            for (int j = 0; j < 4; j++) bv[j] = *(float4*)&Bs[(c0 + j) * 20 + kk];
#pragma unroll
            for (int i = 0; i < 4; i++)
#pragma unroll
                for (int j = 0; j < 4; j++) {
                    acc[i][j] += av[i].x * bv[j].x;
                    acc[i][j] += av[i].y * bv[j].y;
                    acc[i][j] += av[i].z * bv[j].z;
                    acc[i][j] += av[i].w * bv[j].w;
                }
        }
    }

    const float pa = prelu_a[0];
    const float4 bz = *(const float4*)(bias + d0 + c0);
#pragma unroll
    for (int i = 0; i < 4; i++) {
        const int n = n0 + r0 + i;
        const int bb = n >> 10;          // n / T_
        const int t = n & (T_ - 1);      // n % T_
        float h0 = acc[i][0] + bz.x;
        float h1 = acc[i][1] + bz.y;
        float h2 = acc[i][2] + bz.z;
        float h3 = acc[i][3] + bz.w;
        h0 = h0 >= 0.0f ? h0 : pa * h0;
        h1 = h1 >= 0.0f ? h1 : pa * h1;
        h2 = h2 >= 0.0f ? h2 : pa * h2;
        h3 = h3 >= 0.0f ? h3 : pa * h3;
        *(float4*)(out0 + (size_t)t * BD_ + (size_t)bb * D_ + d0 + c0) =
            make_float4(h0, h1, h2, h3);
    }
}

// ---------------------------------------------------------------------------
extern "C" void kernel_launch(void* const* d_in, const int* in_sizes, int n_in,
                              void* d_out, int out_size, void* d_ws, size_t ws_size,
                              hipStream_t stream)
{
    const float* inputs  = (const float*)d_in[0];   // [B,T,768]
    const float* context = (const float*)d_in[1];   // [B,S,768]
    const float* W_out   = (const float*)d_in[2];   // [768,1536]
    const float* b_out   = (const float*)d_in[3];   // [768]
    const float* w_scale = (const float*)d_in[4];
    const float* b_scale = (const float*)d_in[5];
    const float* prelu_a = (const float*)d_in[6];

    float* out0 = (float*)d_out;                          // [T,B,768]
    float* out2 = out0 + (size_t)T_ * B_ * D_;            // [T,B,S] (av_g)

    float* c_ws = (float*)d_ws;                           // [B,T,768]
    float* gate = c_ws + (size_t)B_ * T_ * D_;            // [B,S]

    // 1. scores -> out2
    gemm_scores<<<dim3(S_ / 64, T_ / 64, B_), 256, 0, stream>>>(inputs, context, out2);
    // 2. softmax in place
    softmax_rows<<<B_ * T_, 256, 0, stream>>>(out2);
    // 3. gate
    colsum_gate<<<dim3(S_ / 256, B_), 256, 0, stream>>>(out2, gate);
    // 4. av_g in place
    scale_av<<<(int)(((size_t)T_ * B_ * S_ / 4) / 256), 256, 0, stream>>>(out2, gate);
    // 5. c = av_g @ ctx (+affine)
    gemm_ctx<<<dim3(D_ / 64, T_ / 64, B_), 256, 0, stream>>>(out2, context, w_scale, b_scale, c_ws);
    // 6. h = concat @ W^T (+bias, prelu) -> out0
    gemm_out<<<dim3(D_ / 64, (B_ * T_) / 64), 256, 0, stream>>>(c_ws, inputs, W_out, b_out, prelu_a, out0);
}

// Round 2
// 1486.220 us; speedup vs baseline: 1.7354x; 1.7354x over previous
//
#include <hip/hip_runtime.h>

#define B_ 16
#define T_ 1024
#define S_ 1024
#define D_ 768      // ENC == DEC
#define K3_ 1536    // D_ + D_
#define BS_ (B_ * S_)   // 16384
#define BD_ (B_ * D_)   // 12288
#define PAD_ 17         // BK(16) + 1: fragment reads at 4-row stride hit
                        // banks 4g mod 32 -> every bank exactly 2x (free, m136)

// Shared 128x128 fp32 macro-tile, 8x8 micro-tile as two 4x4 quadrant pairs.
// tr4/tc4: thread's 4-row/4-col group base; rows {g*64+tr4+i}, cols {h*64+tc4+j}.

#define GEMM_PROLOG() \
    const int tid = threadIdx.x; \
    const int tr4 = (tid >> 4) * 4; \
    const int tc4 = (tid & 15) * 4; \
    const int srow = tid >> 2; \
    const int scol = (tid & 3) * 4; \
    float acc[2][2][4][4] = {};

#define GEMM_INNER() \
    _Pragma("unroll") \
    for (int kk = 0; kk < 16; kk += 4) { \
        float4 af[2][4], bf[2][4]; \
        _Pragma("unroll") \
        for (int g = 0; g < 2; g++) \
            _Pragma("unroll") \
            for (int i = 0; i < 4; i++) \
                af[g][i] = *(float4*)&As[(g * 64 + tr4 + i) * PAD_ + kk]; \
        _Pragma("unroll") \
        for (int h = 0; h < 2; h++) \
            _Pragma("unroll") \
            for (int j = 0; j < 4; j++) \
                bf[h][j] = *(float4*)&Bs[(h * 64 + tc4 + j) * PAD_ + kk]; \
        _Pragma("unroll") \
        for (int g = 0; g < 2; g++) \
            _Pragma("unroll") \
            for (int h = 0; h < 2; h++) \
                _Pragma("unroll") \
                for (int i = 0; i < 4; i++) \
                    _Pragma("unroll") \
                    for (int j = 0; j < 4; j++) { \
                        acc[g][h][i][j] += af[g][i].x * bf[h][j].x; \
                        acc[g][h][i][j] += af[g][i].y * bf[h][j].y; \
                        acc[g][h][i][j] += af[g][i].z * bf[h][j].z; \
                        acc[g][h][i][j] += af[g][i].w * bf[h][j].w; \
                    } \
    }

// ---------------------------------------------------------------------------
// GEMM1: scores[t,s] = sum_k inputs[b,t,k] * ctx[b,s,k]   (NT)
// writes directly into out2 laid out [T, B, S]
// ---------------------------------------------------------------------------
__global__ __launch_bounds__(256) void gemm_scores(
    const float* __restrict__ inp, const float* __restrict__ ctx,
    float* __restrict__ out2)
{
    const int b  = blockIdx.z;
    const int t0 = blockIdx.y * 128;
    const int s0 = blockIdx.x * 128;
    const float* A  = inp + (size_t)b * T_ * D_;
    const float* Bm = ctx + (size_t)b * S_ * D_;

    __shared__ float As[128 * PAD_];
    __shared__ float Bs[128 * PAD_];

    GEMM_PROLOG();

    for (int kb = 0; kb < D_; kb += 16) {
        float4 a0 = *(const float4*)(A  + (size_t)(t0 + srow) * D_ + kb + scol);
        float4 a1 = *(const float4*)(A  + (size_t)(t0 + 64 + srow) * D_ + kb + scol);
        float4 b0 = *(const float4*)(Bm + (size_t)(s0 + srow) * D_ + kb + scol);
        float4 b1 = *(const float4*)(Bm + (size_t)(s0 + 64 + srow) * D_ + kb + scol);
        __syncthreads();
        *(float4*)&As[srow * PAD_ + scol] = a0;
        *(float4*)&As[(64 + srow) * PAD_ + scol] = a1;
        *(float4*)&Bs[srow * PAD_ + scol] = b0;
        *(float4*)&Bs[(64 + srow) * PAD_ + scol] = b1;
        __syncthreads();
        GEMM_INNER();
    }

#pragma unroll
    for (int g = 0; g < 2; g++)
#pragma unroll
    for (int i = 0; i < 4; i++)
#pragma unroll
    for (int h = 0; h < 2; h++) {
        const int t = t0 + g * 64 + tr4 + i;
        const int s = s0 + h * 64 + tc4;
        *(float4*)(out2 + (size_t)t * BS_ + (size_t)b * S_ + s) =
            make_float4(acc[g][h][i][0], acc[g][h][i][1],
                        acc[g][h][i][2], acc[g][h][i][3]);
    }
}

// ---------------------------------------------------------------------------
// Softmax over S, in place on out2 rows (row = out2[t*B*S + b*S + :])
// ---------------------------------------------------------------------------
__global__ __launch_bounds__(256) void softmax_rows(float* __restrict__ av)
{
    const int bid = blockIdx.x;
    const int b = bid & (B_ - 1);
    const int t = bid / B_;
    float* row = av + (size_t)t * BS_ + (size_t)b * S_;
    const int tid = threadIdx.x;

    float4 v = ((float4*)row)[tid];
    float m = fmaxf(fmaxf(v.x, v.y), fmaxf(v.z, v.w));

    __shared__ float red[256];
    red[tid] = m;
    __syncthreads();
    for (int off = 128; off > 0; off >>= 1) {
        if (tid < off) red[tid] = fmaxf(red[tid], red[tid + off]);
        __syncthreads();
    }
    m = red[0];
    __syncthreads();

    float4 e;
    e.x = __expf(v.x - m); e.y = __expf(v.y - m);
    e.z = __expf(v.z - m); e.w = __expf(v.w - m);
    float s = e.x + e.y + e.z + e.w;
    red[tid] = s;
    __syncthreads();
    for (int off = 128; off > 0; off >>= 1) {
        if (tid < off) red[tid] += red[tid + off];
        __syncthreads();
    }
    const float inv = 1.0f / red[0];
    e.x *= inv; e.y *= inv; e.z *= inv; e.w *= inv;
    ((float4*)row)[tid] = e;
}

// ---------------------------------------------------------------------------
// gate[b,s] = sigmoid(sum_t av[t,b,s]) * (1/S)      (pooled == 1/S exactly)
// ---------------------------------------------------------------------------
__global__ __launch_bounds__(256) void colsum_gate(
    const float* __restrict__ av, float* __restrict__ gate)
{
    const int b = blockIdx.y;
    const int s = blockIdx.x * 256 + threadIdx.x;
    const float* col = av + (size_t)b * S_ + s;
    float sum = 0.0f;
#pragma unroll 8
    for (int t = 0; t < T_; t++) sum += col[(size_t)t * BS_];
    const float g = 1.0f / (1.0f + __expf(-sum));
    gate[b * S_ + s] = g * (1.0f / (float)S_);
}

// ---------------------------------------------------------------------------
// av_g = av * gate[b,s]  (in place on out2)
// ---------------------------------------------------------------------------
__global__ __launch_bounds__(256) void scale_av(
    float* __restrict__ av, const float* __restrict__ gate)
{
    const size_t i4 = (size_t)blockIdx.x * 256 + threadIdx.x;   // float4 index
    const size_t flat = i4 * 4;
    const int s = (int)(flat & (S_ - 1));
    const int b = (int)((flat >> 10) & (B_ - 1));
    float4 v = ((float4*)av)[i4];
    const float4 g = ((const float4*)gate)[(b * S_ + s) >> 2];
    v.x *= g.x; v.y *= g.y; v.z *= g.z; v.w *= g.w;
    ((float4*)av)[i4] = v;
}

// ---------------------------------------------------------------------------
// GEMM2: c[b,t,d] = (sum_s av_g[t,b,s] * ctx[b,s,d]) * w_scale + b_scale
// A: [t][s] s-contiguous; B: ctx[s][d] d-contiguous -> transposed staging
// ---------------------------------------------------------------------------
__global__ __launch_bounds__(256) void gemm_ctx(
    const float* __restrict__ avg, const float* __restrict__ ctx,
    const float* __restrict__ w_scale, const float* __restrict__ b_scale,
    float* __restrict__ c_ws)
{
    const int b  = blockIdx.z;
    const int t0 = blockIdx.y * 128;
    const int d0 = blockIdx.x * 128;

    __shared__ float As[128 * PAD_];
    __shared__ float Bs[128 * PAD_];   // [d_local][s_local]

    GEMM_PROLOG();

    const int br = tid >> 4;          // 0..15  (s within tile)
    const int bc = (tid & 15) * 4;    // 0..60  (d within half-tile)

    for (int sb = 0; sb < S_; sb += 16) {
        float4 a0 = *(const float4*)(avg + (size_t)(t0 + srow) * BS_ + (size_t)b * S_ + sb + scol);
        float4 a1 = *(const float4*)(avg + (size_t)(t0 + 64 + srow) * BS_ + (size_t)b * S_ + sb + scol);
        float4 b0 = *(const float4*)(ctx + (size_t)b * S_ * D_ + (size_t)(sb + br) * D_ + d0 + bc);
        float4 b1 = *(const float4*)(ctx + (size_t)b * S_ * D_ + (size_t)(sb + br) * D_ + d0 + 64 + bc);
        __syncthreads();
        *(float4*)&As[srow * PAD_ + scol] = a0;
        *(float4*)&As[(64 + srow) * PAD_ + scol] = a1;
        Bs[(bc + 0) * PAD_ + br] = b0.x;
        Bs[(bc + 1) * PAD_ + br] = b0.y;
        Bs[(bc + 2) * PAD_ + br] = b0.z;
        Bs[(bc + 3) * PAD_ + br] = b0.w;
        Bs[(64 + bc + 0) * PAD_ + br] = b1.x;
        Bs[(64 + bc + 1) * PAD_ + br] = b1.y;
        Bs[(64 + bc + 2) * PAD_ + br] = b1.z;
        Bs[(64 + bc + 3) * PAD_ + br] = b1.w;
        __syncthreads();
        GEMM_INNER();
    }

    const float ws = w_scale[0], bsc = b_scale[0];
#pragma unroll
    for (int g = 0; g < 2; g++)
#pragma unroll
    for (int i = 0; i < 4; i++)
#pragma unroll
    for (int h = 0; h < 2; h++) {
        const int t = t0 + g * 64 + tr4 + i;
        const int d = d0 + h * 64 + tc4;
        *(float4*)(c_ws + ((size_t)b * T_ + t) * D_ + d) =
            make_float4(acc[g][h][i][0] * ws + bsc, acc[g][h][i][1] * ws + bsc,
                        acc[g][h][i][2] * ws + bsc, acc[g][h][i][3] * ws + bsc);
    }
}

// ---------------------------------------------------------------------------
// GEMM3: h[n,d] = prelu( sum_k concat[n,k] * W[d,k] + b_out[d] )
// concat[n,k] = k < D ? c_ws[n,k] : inputs[n,k-D];  n = b*T + t
// write to out0 laid out [T, B, D]
// ---------------------------------------------------------------------------
__global__ __launch_bounds__(256) void gemm_out(
    const float* __restrict__ c_ws, const float* __restrict__ inp,
    const float* __restrict__ W, const float* __restrict__ bias,
    const float* __restrict__ prelu_a, float* __restrict__ out0)
{
    const int n0 = blockIdx.y * 128;
    const int d0 = blockIdx.x * 128;

    __shared__ float As[128 * PAD_];
    __shared__ float Bs[128 * PAD_];

    GEMM_PROLOG();

    for (int kb = 0; kb < K3_; kb += 16) {
        const int k = kb + scol;
        const float* base0 = (k < D_) ? (c_ws + (size_t)(n0 + srow) * D_ + k)
                                      : (inp + (size_t)(n0 + srow) * D_ + (k - D_));
        const float* base1 = (k < D_) ? (c_ws + (size_t)(n0 + 64 + srow) * D_ + k)
                                      : (inp + (size_t)(n0 + 64 + srow) * D_ + (k - D_));
        float4 a0 = *(const float4*)base0;
        float4 a1 = *(const float4*)base1;
        float4 b0 = *(const float4*)(W + (size_t)(d0 + srow) * K3_ + kb + scol);
        float4 b1 = *(const float4*)(W + (size_t)(d0 + 64 + srow) * K3_ + kb + scol);
        __syncthreads();
        *(float4*)&As[srow * PAD_ + scol] = a0;
        *(float4*)&As[(64 + srow) * PAD_ + scol] = a1;
        *(float4*)&Bs[srow * PAD_ + scol] = b0;
        *(float4*)&Bs[(64 + srow) * PAD_ + scol] = b1;
        __syncthreads();
        GEMM_INNER();
    }

    const float pa = prelu_a[0];
#pragma unroll
    for (int g = 0; g < 2; g++)
#pragma unroll
    for (int i = 0; i < 4; i++)
#pragma unroll
    for (int h = 0; h < 2; h++) {
        const int n = n0 + g * 64 + tr4 + i;
        const int bb = n >> 10;          // n / T_
        const int t = n & (T_ - 1);      // n % T_
        const int d = d0 + h * 64 + tc4;
        const float4 bz = *(const float4*)(bias + d);
        float h0 = acc[g][h][i][0] + bz.x;
        float h1 = acc[g][h][i][1] + bz.y;
        float h2 = acc[g][h][i][2] + bz.z;
        float h3 = acc[g][h][i][3] + bz.w;
        h0 = h0 >= 0.0f ? h0 : pa * h0;
        h1 = h1 >= 0.0f ? h1 : pa * h1;
        h2 = h2 >= 0.0f ? h2 : pa * h2;
        h3 = h3 >= 0.0f ? h3 : pa * h3;
        *(float4*)(out0 + (size_t)t * BD_ + (size_t)bb * D_ + d) =
            make_float4(h0, h1, h2, h3);
    }
}

// ---------------------------------------------------------------------------
extern "C" void kernel_launch(void* const* d_in, const int* in_sizes, int n_in,
                              void* d_out, int out_size, void* d_ws, size_t ws_size,
                              hipStream_t stream)
{
    const float* inputs  = (const float*)d_in[0];   // [B,T,768]
    const float* context = (const float*)d_in[1];   // [B,S,768]
    const float* W_out   = (const float*)d_in[2];   // [768,1536]
    const float* b_out   = (const float*)d_in[3];   // [768]
    const float* w_scale = (const float*)d_in[4];
    const float* b_scale = (const float*)d_in[5];
    const float* prelu_a = (const float*)d_in[6];

    float* out0 = (float*)d_out;                          // [T,B,768]
    float* out2 = out0 + (size_t)T_ * B_ * D_;            // [T,B,S] (av_g)

    float* c_ws = (float*)d_ws;                           // [B,T,768]
    float* gate = c_ws + (size_t)B_ * T_ * D_;            // [B,S]

    // 1. scores -> out2
    gemm_scores<<<dim3(S_ / 128, T_ / 128, B_), 256, 0, stream>>>(inputs, context, out2);
    // 2. softmax in place
    softmax_rows<<<B_ * T_, 256, 0, stream>>>(out2);
    // 3. gate
    colsum_gate<<<dim3(S_ / 256, B_), 256, 0, stream>>>(out2, gate);
    // 4. av_g in place
    scale_av<<<(int)(((size_t)T_ * B_ * S_ / 4) / 256), 256, 0, stream>>>(out2, gate);
    // 5. c = av_g @ ctx (+affine)
    gemm_ctx<<<dim3(D_ / 128, T_ / 128, B_), 256, 0, stream>>>(out2, context, w_scale, b_scale, c_ws);
    // 6. h = concat @ W^T (+bias, prelu) -> out0
    gemm_out<<<dim3(D_ / 128, (B_ * T_) / 128), 256, 0, stream>>>(c_ws, inputs, W_out, b_out, prelu_a, out0);
}

// Round 4
// 792.198 us; speedup vs baseline: 3.2558x; 1.8761x over previous
//
#include <hip/hip_runtime.h>

#define B_ 16
#define T_ 1024
#define S_ 1024
#define D_ 768      // ENC == DEC
#define K3_ 1536    // D_ + D_
#define BS_ (B_ * S_)   // 16384
#define BD_ (B_ * D_)   // 12288
#define PAD_ 17         // fp32 GEMM LDS pad (R1, conflict-free)
#define BPAD_ 40        // bf16 LDS row stride: 32 k + 8 pad (80 B, 16B-aligned)

typedef __attribute__((ext_vector_type(8))) short short8;
typedef __attribute__((ext_vector_type(4))) float float4v;

// fp32 -> bf16 (RNE)
__device__ __forceinline__ unsigned short f2bf(float x) {
    unsigned u = __builtin_bit_cast(unsigned, x);
    unsigned r = (u + 0x7fff + ((u >> 16) & 1)) >> 16;
    return (unsigned short)r;
}
// pack two fp32 -> bf16x2 in a u32 (lo=a, hi=b)
__device__ __forceinline__ unsigned pk2(float a, float b) {
    return (unsigned)f2bf(a) | ((unsigned)f2bf(b) << 16);
}
__device__ __forceinline__ uint4 cvt8(const float4 a, const float4 b) {
    return make_uint4(pk2(a.x, a.y), pk2(a.z, a.w), pk2(b.x, b.y), pk2(b.z, b.w));
}

// ===========================================================================
// fp32 GEMM1 (unchanged from R1): scores = inputs @ ctx^T -> out2 [T,B,S]
// ===========================================================================
#define GEMM_PROLOG() \
    const int tid = threadIdx.x; \
    const int tr4 = (tid >> 4) * 4; \
    const int tc4 = (tid & 15) * 4; \
    const int srow = tid >> 2; \
    const int scol = (tid & 3) * 4; \
    float acc[2][2][4][4] = {};

#define GEMM_INNER() \
    _Pragma("unroll") \
    for (int kk = 0; kk < 16; kk += 4) { \
        float4 af[2][4], bfr[2][4]; \
        _Pragma("unroll") \
        for (int g = 0; g < 2; g++) \
            _Pragma("unroll") \
            for (int i = 0; i < 4; i++) \
                af[g][i] = *(float4*)&As[(g * 64 + tr4 + i) * PAD_ + kk]; \
        _Pragma("unroll") \
        for (int h = 0; h < 2; h++) \
            _Pragma("unroll") \
            for (int j = 0; j < 4; j++) \
                bfr[h][j] = *(float4*)&Bs[(h * 64 + tc4 + j) * PAD_ + kk]; \
        _Pragma("unroll") \
        for (int g = 0; g < 2; g++) \
            _Pragma("unroll") \
            for (int h = 0; h < 2; h++) \
                _Pragma("unroll") \
                for (int i = 0; i < 4; i++) \
                    _Pragma("unroll") \
                    for (int j = 0; j < 4; j++) { \
                        acc[g][h][i][j] += af[g][i].x * bfr[h][j].x; \
                        acc[g][h][i][j] += af[g][i].y * bfr[h][j].y; \
                        acc[g][h][i][j] += af[g][i].z * bfr[h][j].z; \
                        acc[g][h][i][j] += af[g][i].w * bfr[h][j].w; \
                    } \
    }

__global__ __launch_bounds__(256) void gemm_scores(
    const float* __restrict__ inp, const float* __restrict__ ctx,
    float* __restrict__ out2)
{
    const int b  = blockIdx.z;
    const int t0 = blockIdx.y * 128;
    const int s0 = blockIdx.x * 128;
    const float* A  = inp + (size_t)b * T_ * D_;
    const float* Bm = ctx + (size_t)b * S_ * D_;

    __shared__ float As[128 * PAD_];
    __shared__ float Bs[128 * PAD_];

    GEMM_PROLOG();

    for (int kb = 0; kb < D_; kb += 16) {
        float4 a0 = *(const float4*)(A  + (size_t)(t0 + srow) * D_ + kb + scol);
        float4 a1 = *(const float4*)(A  + (size_t)(t0 + 64 + srow) * D_ + kb + scol);
        float4 b0 = *(const float4*)(Bm + (size_t)(s0 + srow) * D_ + kb + scol);
        float4 b1 = *(const float4*)(Bm + (size_t)(s0 + 64 + srow) * D_ + kb + scol);
        __syncthreads();
        *(float4*)&As[srow * PAD_ + scol] = a0;
        *(float4*)&As[(64 + srow) * PAD_ + scol] = a1;
        *(float4*)&Bs[srow * PAD_ + scol] = b0;
        *(float4*)&Bs[(64 + srow) * PAD_ + scol] = b1;
        __syncthreads();
        GEMM_INNER();
    }

#pragma unroll
    for (int g = 0; g < 2; g++)
#pragma unroll
    for (int i = 0; i < 4; i++)
#pragma unroll
    for (int h = 0; h < 2; h++) {
        const int t = t0 + g * 64 + tr4 + i;
        const int s = s0 + h * 64 + tc4;
        *(float4*)(out2 + (size_t)t * BS_ + (size_t)b * S_ + s) =
            make_float4(acc[g][h][i][0], acc[g][h][i][1],
                        acc[g][h][i][2], acc[g][h][i][3]);
    }
}

// ===========================================================================
// softmax / gate / scale  (unchanged)
// ===========================================================================
__global__ __launch_bounds__(256) void softmax_rows(float* __restrict__ av)
{
    const int bid = blockIdx.x;
    const int b = bid & (B_ - 1);
    const int t = bid / B_;
    float* row = av + (size_t)t * BS_ + (size_t)b * S_;
    const int tid = threadIdx.x;

    float4 v = ((float4*)row)[tid];
    float m = fmaxf(fmaxf(v.x, v.y), fmaxf(v.z, v.w));

    __shared__ float red[256];
    red[tid] = m;
    __syncthreads();
    for (int off = 128; off > 0; off >>= 1) {
        if (tid < off) red[tid] = fmaxf(red[tid], red[tid + off]);
        __syncthreads();
    }
    m = red[0];
    __syncthreads();

    float4 e;
    e.x = __expf(v.x - m); e.y = __expf(v.y - m);
    e.z = __expf(v.z - m); e.w = __expf(v.w - m);
    float s = e.x + e.y + e.z + e.w;
    red[tid] = s;
    __syncthreads();
    for (int off = 128; off > 0; off >>= 1) {
        if (tid < off) red[tid] += red[tid + off];
        __syncthreads();
    }
    const float inv = 1.0f / red[0];
    e.x *= inv; e.y *= inv; e.z *= inv; e.w *= inv;
    ((float4*)row)[tid] = e;
}

__global__ __launch_bounds__(256) void colsum_gate(
    const float* __restrict__ av, float* __restrict__ gate)
{
    const int b = blockIdx.y;
    const int s = blockIdx.x * 256 + threadIdx.x;
    const float* col = av + (size_t)b * S_ + s;
    float sum = 0.0f;
#pragma unroll 8
    for (int t = 0; t < T_; t++) sum += col[(size_t)t * BS_];
    const float g = 1.0f / (1.0f + __expf(-sum));
    gate[b * S_ + s] = g * (1.0f / (float)S_);
}

__global__ __launch_bounds__(256) void scale_av(
    float* __restrict__ av, const float* __restrict__ gate)
{
    const size_t i4 = (size_t)blockIdx.x * 256 + threadIdx.x;
    const size_t flat = i4 * 4;
    const int s = (int)(flat & (S_ - 1));
    const int b = (int)((flat >> 10) & (B_ - 1));
    float4 v = ((float4*)av)[i4];
    const float4 g = ((const float4*)gate)[(b * S_ + s) >> 2];
    v.x *= g.x; v.y *= g.y; v.z *= g.z; v.w *= g.w;
    ((float4*)av)[i4] = v;
}

// ===========================================================================
// ctx [b][s][d] fp32 -> ctxT [b][d][s] bf16  (64x64 tiles via LDS)
// ===========================================================================
__global__ __launch_bounds__(256) void transpose_ctx(
    const float* __restrict__ ctx, unsigned short* __restrict__ ctxT)
{
    const int b  = blockIdx.z;
    const int d0 = blockIdx.y * 64;
    const int s0 = blockIdx.x * 64;
    __shared__ unsigned short Ts[64 * 68];   // [d][s], stride 68 (136 B, 8B-aligned)

    const int tid = threadIdx.x;
    const int srel = tid >> 4;              // 0..15
    const int dcol = (tid & 15) * 4;        // 0..60
#pragma unroll
    for (int r = 0; r < 4; r++) {
        const int s = srel + r * 16;
        float4 v = *(const float4*)(ctx + ((size_t)b * S_ + s0 + s) * D_ + d0 + dcol);
        Ts[(dcol + 0) * 68 + s] = f2bf(v.x);
        Ts[(dcol + 1) * 68 + s] = f2bf(v.y);
        Ts[(dcol + 2) * 68 + s] = f2bf(v.z);
        Ts[(dcol + 3) * 68 + s] = f2bf(v.w);
    }
    __syncthreads();
    const int drow = tid >> 2;              // 0..63
    const int scg  = (tid & 3) * 16;        // 0..48
    unsigned short* dst = ctxT + ((size_t)b * D_ + d0 + drow) * S_ + s0 + scg;
#pragma unroll
    for (int p = 0; p < 4; p++) {
        uint2 u = *(const uint2*)&Ts[drow * 68 + scg + p * 4];
        *(uint2*)(dst + p * 4) = u;
    }
}

// ===========================================================================
// bf16 MFMA GEMM common: 128x128 block, 4 waves (2x2), wave=64x64 of 16x16x32
// LDS: As[128][BPAD_], Bs[128][BPAD_] ushort (k-contiguous rows)
// ===========================================================================
#define MFMA_PROLOG() \
    const int tid  = threadIdx.x; \
    const int w    = tid >> 6; \
    const int wm   = (w >> 1) * 64; \
    const int wn   = (w & 1) * 64; \
    const int lane = tid & 63; \
    const int q    = lane >> 4; \
    const int lr   = lane & 15; \
    const int arow = tid >> 1; \
    const int acg  = (tid & 1) * 16; \
    float4v acc[4][4] = {};

#define MFMA_COMPUTE() \
    { \
        short8 afr[4], bfr[4]; \
        _Pragma("unroll") \
        for (int i = 0; i < 4; i++) \
            afr[i] = *(const short8*)&As[(wm + i * 16 + lr) * BPAD_ + q * 8]; \
        _Pragma("unroll") \
        for (int j = 0; j < 4; j++) \
            bfr[j] = *(const short8*)&Bs[(wn + j * 16 + lr) * BPAD_ + q * 8]; \
        _Pragma("unroll") \
        for (int i = 0; i < 4; i++) \
            _Pragma("unroll") \
            for (int j = 0; j < 4; j++) \
                acc[i][j] = __builtin_amdgcn_mfma_f32_16x16x32_bf16( \
                    afr[i], bfr[j], acc[i][j], 0, 0, 0); \
    }

// GEMM2: c_bf[b,t,d] = bf16( (av_g @ ctx) * w_scale + b_scale )
__global__ __launch_bounds__(256) void gemm_ctx_mfma(
    const float* __restrict__ avg, const unsigned short* __restrict__ ctxT,
    const float* __restrict__ w_scale, const float* __restrict__ b_scale,
    unsigned short* __restrict__ c_bf)
{
    const int b  = blockIdx.z;
    const int t0 = blockIdx.y * 128;
    const int d0 = blockIdx.x * 128;

    __shared__ __align__(16) unsigned short As[128 * BPAD_];
    __shared__ __align__(16) unsigned short Bs[128 * BPAD_];

    MFMA_PROLOG();

    const float* asrc = avg + (size_t)(t0 + arow) * BS_ + (size_t)b * S_;
    const unsigned short* bsrc = ctxT + ((size_t)b * D_ + d0 + arow) * S_;

    for (int sb = 0; sb < S_; sb += 32) {
        const float* ap = asrc + sb + acg;
        float4 f0 = ((const float4*)ap)[0];
        float4 f1 = ((const float4*)ap)[1];
        float4 f2 = ((const float4*)ap)[2];
        float4 f3 = ((const float4*)ap)[3];
        uint4 bu0 = ((const uint4*)(bsrc + sb + acg))[0];
        uint4 bu1 = ((const uint4*)(bsrc + sb + acg))[1];
        uint4 au0 = cvt8(f0, f1);
        uint4 au1 = cvt8(f2, f3);
        __syncthreads();
        *(uint4*)&As[arow * BPAD_ + acg]     = au0;
        *(uint4*)&As[arow * BPAD_ + acg + 8] = au1;
        *(uint4*)&Bs[arow * BPAD_ + acg]     = bu0;
        *(uint4*)&Bs[arow * BPAD_ + acg + 8] = bu1;
        __syncthreads();
        MFMA_COMPUTE();
    }

    const float wsc = w_scale[0], bsc = b_scale[0];
#pragma unroll
    for (int i = 0; i < 4; i++)
#pragma unroll
    for (int j = 0; j < 4; j++) {
        const int d = d0 + wn + j * 16 + lr;
#pragma unroll
        for (int r = 0; r < 4; r++) {
            const int t = t0 + wm + i * 16 + q * 4 + r;
            c_bf[((size_t)b * T_ + t) * D_ + d] = f2bf(acc[i][j][r] * wsc + bsc);
        }
    }
}

// GEMM3: h = prelu(concat(c_bf, inputs) @ W^T + bias) -> out0 [T,B,D]
__global__ __launch_bounds__(256) void gemm_out_mfma(
    const unsigned short* __restrict__ c_bf, const float* __restrict__ inp,
    const float* __restrict__ W, const float* __restrict__ bias,
    const float* __restrict__ prelu_a, float* __restrict__ out0)
{
    const int n0 = blockIdx.y * 128;
    const int d0 = blockIdx.x * 128;

    __shared__ __align__(16) unsigned short As[128 * BPAD_];
    __shared__ __align__(16) unsigned short Bs[128 * BPAD_];

    MFMA_PROLOG();

    for (int kb = 0; kb < K3_; kb += 32) {
        uint4 au0, au1, bu0, bu1;
        if (kb < D_) {   // block-uniform branch
            const unsigned short* ap = c_bf + (size_t)(n0 + arow) * D_ + kb + acg;
            au0 = ((const uint4*)ap)[0];
            au1 = ((const uint4*)ap)[1];
        } else {
            const float* ap = inp + (size_t)(n0 + arow) * D_ + (kb - D_) + acg;
            float4 f0 = ((const float4*)ap)[0];
            float4 f1 = ((const float4*)ap)[1];
            float4 f2 = ((const float4*)ap)[2];
            float4 f3 = ((const float4*)ap)[3];
            au0 = cvt8(f0, f1);
            au1 = cvt8(f2, f3);
        }
        {
            const float* bp = W + (size_t)(d0 + arow) * K3_ + kb + acg;
            float4 g0 = ((const float4*)bp)[0];
            float4 g1 = ((const float4*)bp)[1];
            float4 g2 = ((const float4*)bp)[2];
            float4 g3 = ((const float4*)bp)[3];
            bu0 = cvt8(g0, g1);
            bu1 = cvt8(g2, g3);
        }
        __syncthreads();
        *(uint4*)&As[arow * BPAD_ + acg]     = au0;
        *(uint4*)&As[arow * BPAD_ + acg + 8] = au1;
        *(uint4*)&Bs[arow * BPAD_ + acg]     = bu0;
        *(uint4*)&Bs[arow * BPAD_ + acg + 8] = bu1;
        __syncthreads();
        MFMA_COMPUTE();
    }

    const float pa = prelu_a[0];
#pragma unroll
    for (int j = 0; j < 4; j++) {
        const int d = d0 + wn + j * 16 + lr;
        const float bz = bias[d];
#pragma unroll
        for (int i = 0; i < 4; i++) {
#pragma unroll
            for (int r = 0; r < 4; r++) {
                const int n = n0 + wm + i * 16 + q * 4 + r;
                const int bb = n >> 10;
                const int t = n & (T_ - 1);
                float h = acc[i][j][r] + bz;
                h = h >= 0.0f ? h : pa * h;
                out0[(size_t)t * BD_ + (size_t)bb * D_ + d] = h;
            }
        }
    }
}

// ===========================================================================
extern "C" void kernel_launch(void* const* d_in, const int* in_sizes, int n_in,
                              void* d_out, int out_size, void* d_ws, size_t ws_size,
                              hipStream_t stream)
{
    const float* inputs  = (const float*)d_in[0];   // [B,T,768]
    const float* context = (const float*)d_in[1];   // [B,S,768]
    const float* W_out   = (const float*)d_in[2];   // [768,1536]
    const float* b_out   = (const float*)d_in[3];   // [768]
    const float* w_scale = (const float*)d_in[4];
    const float* b_scale = (const float*)d_in[5];
    const float* prelu_a = (const float*)d_in[6];

    float* out0 = (float*)d_out;                          // [T,B,768]
    float* out2 = out0 + (size_t)T_ * B_ * D_;            // [T,B,S] (av_g)

    // ws: c_bf (25.2 MB) | ctxT (25.2 MB) | gate (64 KB)
    unsigned short* c_bf = (unsigned short*)d_ws;
    unsigned short* ctxT = c_bf + (size_t)B_ * T_ * D_;
    float* gate = (float*)(ctxT + (size_t)B_ * D_ * S_);

    // 0. ctx -> ctxT bf16 (independent of steps 1-4)
    transpose_ctx<<<dim3(S_ / 64, D_ / 64, B_), 256, 0, stream>>>(context, ctxT);
    // 1. scores -> out2 (fp32: feeds softmax -> output 1, precision-critical)
    gemm_scores<<<dim3(S_ / 128, T_ / 128, B_), 256, 0, stream>>>(inputs, context, out2);
    // 2. softmax in place
    softmax_rows<<<B_ * T_, 256, 0, stream>>>(out2);
    // 3. gate
    colsum_gate<<<dim3(S_ / 256, B_), 256, 0, stream>>>(out2, gate);
    // 4. av_g in place
    scale_av<<<(int)(((size_t)T_ * B_ * S_ / 4) / 256), 256, 0, stream>>>(out2, gate);
    // 5. c = bf16((av_g @ ctx) * ws + bs)   [MFMA]
    gemm_ctx_mfma<<<dim3(D_ / 128, T_ / 128, B_), 256, 0, stream>>>(
        out2, ctxT, w_scale, b_scale, c_bf);
    // 6. h = prelu(concat @ W^T + b) -> out0   [MFMA]
    gemm_out_mfma<<<dim3(D_ / 128, (B_ * T_) / 128), 256, 0, stream>>>(
        c_bf, inputs, W_out, b_out, prelu_a, out0);
}